// Round 3
// baseline (550.119 us; speedup 1.0000x reference)
//
#include <hip/hip_runtime.h>

#define FD 64  // feature dim

// ---------------- Kernel 1: in-degree histogram (int atomics) ----------------
__global__ void deg_kernel(const int* __restrict__ dst, int* __restrict__ degi, int E) {
    int i = blockIdx.x * blockDim.x + threadIdx.x;
    int stride = gridDim.x * blockDim.x;
    for (; i < E; i += stride) {
        atomicAdd(&degi[dst[i]], 1);
    }
}

// ---------------- Kernel 2: dis = (deg + 1)^-1/2 ----------------
__global__ void dis_kernel(const int* __restrict__ degi, float* __restrict__ dis, int N) {
    int i = blockIdx.x * blockDim.x + threadIdx.x;
    if (i < N) {
        dis[i] = rsqrtf((float)degi[i] + 1.0f);
    }
}

// ---------------- Scan (exclusive) of degi -> offs, 3-kernel hierarchical ----------------
#define SCAN_ELEMS 2048  // 256 threads x 8 elements

__global__ void scan1_kernel(const int* __restrict__ degi, int* __restrict__ offs,
                             int* __restrict__ bsums, int N) {
    __shared__ int tsum[256];
    int base = blockIdx.x * SCAN_ELEMS + threadIdx.x * 8;
    int v[8];
    int s = 0;
    #pragma unroll
    for (int k = 0; k < 8; ++k) {
        int idx = base + k;
        v[k] = (idx < N) ? degi[idx] : 0;
        s += v[k];
    }
    tsum[threadIdx.x] = s;
    __syncthreads();
    for (int off = 1; off < 256; off <<= 1) {
        int t = (threadIdx.x >= off) ? tsum[threadIdx.x - off] : 0;
        __syncthreads();
        tsum[threadIdx.x] += t;
        __syncthreads();
    }
    int excl = (threadIdx.x == 0) ? 0 : tsum[threadIdx.x - 1];
    #pragma unroll
    for (int k = 0; k < 8; ++k) {
        int idx = base + k;
        if (idx < N) offs[idx] = excl;
        excl += v[k];
    }
    if (threadIdx.x == 255) bsums[blockIdx.x] = tsum[255];
}

__global__ void scan2_kernel(int* __restrict__ bsums, int nb) {
    __shared__ int t[256];
    int v = (threadIdx.x < nb) ? bsums[threadIdx.x] : 0;
    t[threadIdx.x] = v;
    __syncthreads();
    for (int off = 1; off < 256; off <<= 1) {
        int u = (threadIdx.x >= off) ? t[threadIdx.x - off] : 0;
        __syncthreads();
        t[threadIdx.x] += u;
        __syncthreads();
    }
    if (threadIdx.x < nb) bsums[threadIdx.x] = (threadIdx.x == 0) ? 0 : t[threadIdx.x - 1];
}

__global__ void scan3_kernel(int* __restrict__ offs, const int* __restrict__ bsums, int N) {
    int i = blockIdx.x * blockDim.x + threadIdx.x;
    if (i < N) offs[i] += bsums[i / SCAN_ELEMS];
}

// ---------------- Kernel: fill buckets (CSR column array) ----------------
__global__ void fill_kernel(const int* __restrict__ src, const int* __restrict__ dst,
                            const int* __restrict__ offs, int* __restrict__ cursor,
                            int* __restrict__ bucket, int E) {
    int i = blockIdx.x * blockDim.x + threadIdx.x;
    int stride = gridDim.x * blockDim.x;
    for (; i < E; i += stride) {
        int d = dst[i];
        int pos = atomicAdd(&cursor[d], 1);
        bucket[offs[d] + pos] = src[i];
    }
}

// ---------------- Fused gather + self-loop + normalize + linear ----------------
// 4 waves/block, 16 nodes/wave processed in 4 rounds of 4 (4 node-chains for MLP,
// 4x reuse of each Wt[i][lane] LDS read). Wt padded [64][65]: transpose-store and
// reads both bank-conflict-free. lane = feature index. No atomics, no float LDS
// conflicts.
#define NPB 64  // nodes per block (16 per wave)

__global__ __launch_bounds__(256) void gather_linear_kernel(
        const float* __restrict__ x, const int* __restrict__ offs,
        const int* __restrict__ degi, const int* __restrict__ bucket,
        const float* __restrict__ dis, const float* __restrict__ W,
        float* __restrict__ out, int N) {
    __shared__ float Wt[FD][FD + 1];   // Wt[i][o] = W[o][i], padded
    __shared__ float rows[4][4][FD];   // [wave][k][feature]

    for (int t = threadIdx.x; t < FD * FD; t += 256) {
        Wt[t & 63][t >> 6] = W[t];     // lanes write i=lane, stride 65 -> conflict-free
    }
    __syncthreads();

    int wave = threadIdx.x >> 6;
    int lane = threadIdx.x & 63;
    int base = blockIdx.x * NPB + wave * 16;

    for (int r = 0; r < 4; ++r) {
        int n0 = base + r * 4;

        // ---- gather phase: 4 nodes, 2-unrolled each -> 8 chains in flight ----
        float acc[4] = {0.f, 0.f, 0.f, 0.f};
        #pragma unroll
        for (int k = 0; k < 4; ++k) {
            int n = n0 + k;
            if (n < N) {
                int j   = offs[n];
                int end = j + degi[n];
                for (; j + 1 < end; j += 2) {
                    int s0 = bucket[j];
                    int s1 = bucket[j + 1];
                    float d0 = dis[s0];
                    float d1 = dis[s1];
                    float v0 = x[(size_t)s0 * FD + lane];
                    float v1 = x[(size_t)s1 * FD + lane];
                    acc[k] += v0 * d0 + v1 * d1;
                }
                if (j < end) {
                    int s = bucket[j];
                    acc[k] += x[(size_t)s * FD + lane] * dis[s];
                }
                float dn = dis[n];
                acc[k] = (acc[k] + x[(size_t)n * FD + lane] * dn) * dn;
            }
            rows[wave][k][lane] = acc[k];   // conflict-free (consecutive lanes)
        }
        // wave-local LDS produce->consume: lockstep within wave, no barrier needed

        // ---- epilogue: 4 nodes share each Wt read ----
        float o0 = 0.f, o1 = 0.f, o2 = 0.f, o3 = 0.f;
        #pragma unroll
        for (int i = 0; i < FD; i += 4) {
            float4 r0 = *(const float4*)&rows[wave][0][i];  // broadcast reads
            float4 r1 = *(const float4*)&rows[wave][1][i];
            float4 r2 = *(const float4*)&rows[wave][2][i];
            float4 r3 = *(const float4*)&rows[wave][3][i];
            float w0 = Wt[i + 0][lane];   // stride-65 rows -> conflict-free
            float w1 = Wt[i + 1][lane];
            float w2 = Wt[i + 2][lane];
            float w3 = Wt[i + 3][lane];
            o0 += r0.x * w0 + r0.y * w1 + r0.z * w2 + r0.w * w3;
            o1 += r1.x * w0 + r1.y * w1 + r1.z * w2 + r1.w * w3;
            o2 += r2.x * w0 + r2.y * w1 + r2.z * w2 + r2.w * w3;
            o3 += r3.x * w0 + r3.y * w1 + r3.z * w2 + r3.w * w3;
        }
        if (n0 + 0 < N) out[(size_t)(n0 + 0) * FD + lane] = o0;
        if (n0 + 1 < N) out[(size_t)(n0 + 1) * FD + lane] = o1;
        if (n0 + 2 < N) out[(size_t)(n0 + 2) * FD + lane] = o2;
        if (n0 + 3 < N) out[(size_t)(n0 + 3) * FD + lane] = o3;
    }
}

extern "C" void kernel_launch(void* const* d_in, const int* in_sizes, int n_in,
                              void* d_out, int out_size, void* d_ws, size_t ws_size,
                              hipStream_t stream) {
    const float* x  = (const float*)d_in[0];
    const int*   ei = (const int*)d_in[1];   // [2, E]: src row then dst row
    const float* W  = (const float*)d_in[2];

    const int N = in_sizes[0] / FD;
    const int E = in_sizes[1] / 2;
    const int* src = ei;
    const int* dst = ei + E;

    // Workspace layout: degi[N] | dis[N] | offs[N] | cursor[N] | bsums[1024] | bucket[E]
    char* ws = (char*)d_ws;
    int*   degi   = (int*)ws;                      ws += (size_t)N * 4;
    float* dis    = (float*)ws;                    ws += (size_t)N * 4;
    int*   offs   = (int*)ws;                      ws += (size_t)N * 4;
    int*   cursor = (int*)ws;                      ws += (size_t)N * 4;
    int*   bsums  = (int*)ws;                      ws += 1024 * 4;
    int*   bucket = (int*)ws;

    float* out = (float*)d_out;

    hipMemsetAsync(degi,   0, (size_t)N * 4, stream);
    hipMemsetAsync(cursor, 0, (size_t)N * 4, stream);

    // 1) degree histogram
    deg_kernel<<<2048, 256, 0, stream>>>(dst, degi, E);
    // 2) dis
    dis_kernel<<<(N + 255) / 256, 256, 0, stream>>>(degi, dis, N);
    // 3) exclusive scan degi -> offs
    int nb = (N + SCAN_ELEMS - 1) / SCAN_ELEMS;
    scan1_kernel<<<nb, 256, 0, stream>>>(degi, offs, bsums, N);
    scan2_kernel<<<1, 256, 0, stream>>>(bsums, nb);
    scan3_kernel<<<(N + 255) / 256, 256, 0, stream>>>(offs, bsums, N);
    // 4) fill CSR buckets
    fill_kernel<<<2048, 256, 0, stream>>>(src, dst, offs, cursor, bucket, E);
    // 5) fused gather + self-loop + normalize + linear
    gather_linear_kernel<<<(N + NPB - 1) / NPB, 256, 0, stream>>>(
        x, offs, degi, bucket, dis, W, out, N);
}

// Round 4
// 206.126 us; speedup vs baseline: 2.6688x; 2.6688x over previous
//
#include <hip/hip_runtime.h>

#define FD 64  // feature dim

// ---------------- Kernel 1: in-degree histogram (int atomics) ----------------
__global__ void deg_kernel(const int* __restrict__ dst, int* __restrict__ degi, int E) {
    int i = blockIdx.x * blockDim.x + threadIdx.x;
    int stride = gridDim.x * blockDim.x;
    for (; i < E; i += stride) {
        atomicAdd(&degi[dst[i]], 1);
    }
}

// ---------------- Kernel 2: dis = (deg + 1)^-1/2 ----------------
__global__ void dis_kernel(const int* __restrict__ degi, float* __restrict__ dis, int N) {
    int i = blockIdx.x * blockDim.x + threadIdx.x;
    if (i < N) {
        dis[i] = rsqrtf((float)degi[i] + 1.0f);
    }
}

// ---------------- Scan (exclusive) of degi -> offs, 3-kernel hierarchical ----------------
#define SCAN_ELEMS 2048  // 256 threads x 8 elements

__global__ void scan1_kernel(const int* __restrict__ degi, int* __restrict__ offs,
                             int* __restrict__ bsums, int N) {
    __shared__ int tsum[256];
    int base = blockIdx.x * SCAN_ELEMS + threadIdx.x * 8;
    int v[8];
    int s = 0;
    #pragma unroll
    for (int k = 0; k < 8; ++k) {
        int idx = base + k;
        v[k] = (idx < N) ? degi[idx] : 0;
        s += v[k];
    }
    tsum[threadIdx.x] = s;
    __syncthreads();
    for (int off = 1; off < 256; off <<= 1) {
        int t = (threadIdx.x >= off) ? tsum[threadIdx.x - off] : 0;
        __syncthreads();
        tsum[threadIdx.x] += t;
        __syncthreads();
    }
    int excl = (threadIdx.x == 0) ? 0 : tsum[threadIdx.x - 1];
    #pragma unroll
    for (int k = 0; k < 8; ++k) {
        int idx = base + k;
        if (idx < N) offs[idx] = excl;
        excl += v[k];
    }
    if (threadIdx.x == 255) bsums[blockIdx.x] = tsum[255];
}

__global__ void scan2_kernel(int* __restrict__ bsums, int nb) {
    __shared__ int t[256];
    int v = (threadIdx.x < nb) ? bsums[threadIdx.x] : 0;
    t[threadIdx.x] = v;
    __syncthreads();
    for (int off = 1; off < 256; off <<= 1) {
        int u = (threadIdx.x >= off) ? t[threadIdx.x - off] : 0;
        __syncthreads();
        t[threadIdx.x] += u;
        __syncthreads();
    }
    if (threadIdx.x < nb) bsums[threadIdx.x] = (threadIdx.x == 0) ? 0 : t[threadIdx.x - 1];
}

__global__ void scan3_kernel(int* __restrict__ offs, const int* __restrict__ bsums, int N) {
    int i = blockIdx.x * blockDim.x + threadIdx.x;
    if (i < N) offs[i] += bsums[i / SCAN_ELEMS];
}

// ---------------- Kernel: fill buckets (CSR column array) ----------------
__global__ void fill_kernel(const int* __restrict__ src, const int* __restrict__ dst,
                            const int* __restrict__ offs, int* __restrict__ cursor,
                            int* __restrict__ bucket, int E) {
    int i = blockIdx.x * blockDim.x + threadIdx.x;
    int stride = gridDim.x * blockDim.x;
    for (; i < E; i += stride) {
        int d = dst[i];
        int pos = atomicAdd(&cursor[d], 1);
        bucket[offs[d] + pos] = src[i];
    }
}

// ---------------- Fused gather + self-loop + normalize + linear ----------------
// Round-2 structure (1 node per wave, 4 waves/block, small VGPR footprint, high
// occupancy) + Wt padded [64][65] so the transpose-store AND the Wt[i][lane]
// reads are bank-conflict-free. Gather unrolled 4x for latency hiding.
__global__ __launch_bounds__(256) void gather_linear_kernel(
        const float* __restrict__ x, const int* __restrict__ offs,
        const int* __restrict__ degi, const int* __restrict__ bucket,
        const float* __restrict__ dis, const float* __restrict__ W,
        float* __restrict__ out, int N) {
    __shared__ float Wt[FD][FD + 1];   // Wt[i][o] = W[o][i], padded: conflict-free
    __shared__ float rows[4][FD];

    for (int t = threadIdx.x; t < FD * FD; t += 256) {
        Wt[t & 63][t >> 6] = W[t];     // lane writes row i=lane, stride 65 -> 2-way max
    }
    __syncthreads();

    int wave = threadIdx.x >> 6;
    int lane = threadIdx.x & 63;
    int n = blockIdx.x * 4 + wave;

    if (n < N) {
        int j   = offs[n];
        int end = j + degi[n];
        float acc = 0.0f;
        // 4 independent gather chains in flight
        for (; j + 3 < end; j += 4) {
            int s0 = bucket[j], s1 = bucket[j + 1], s2 = bucket[j + 2], s3 = bucket[j + 3];
            float d0 = dis[s0], d1 = dis[s1], d2 = dis[s2], d3 = dis[s3];
            float v0 = x[(size_t)s0 * FD + lane];
            float v1 = x[(size_t)s1 * FD + lane];
            float v2 = x[(size_t)s2 * FD + lane];
            float v3 = x[(size_t)s3 * FD + lane];
            acc += v0 * d0 + v1 * d1 + v2 * d2 + v3 * d3;
        }
        for (; j < end; ++j) {
            int s = bucket[j];
            acc += x[(size_t)s * FD + lane] * dis[s];
        }
        float dn = dis[n];
        rows[wave][lane] = (acc + x[(size_t)n * FD + lane] * dn) * dn;
    }
    // same-wave produce->consume in LDS: lockstep, no block barrier needed

    if (n < N) {
        float o = 0.0f;
        #pragma unroll
        for (int i = 0; i < FD; i += 4) {
            float4 r = *(const float4*)&rows[wave][i];   // broadcast read
            o += r.x * Wt[i + 0][lane]
               + r.y * Wt[i + 1][lane]
               + r.z * Wt[i + 2][lane]
               + r.w * Wt[i + 3][lane];
        }
        out[(size_t)n * FD + lane] = o;
    }
}

extern "C" void kernel_launch(void* const* d_in, const int* in_sizes, int n_in,
                              void* d_out, int out_size, void* d_ws, size_t ws_size,
                              hipStream_t stream) {
    const float* x  = (const float*)d_in[0];
    const int*   ei = (const int*)d_in[1];   // [2, E]: src row then dst row
    const float* W  = (const float*)d_in[2];

    const int N = in_sizes[0] / FD;
    const int E = in_sizes[1] / 2;
    const int* src = ei;
    const int* dst = ei + E;

    // Workspace layout: degi[N] | dis[N] | offs[N] | cursor[N] | bsums[1024] | bucket[E]
    char* ws = (char*)d_ws;
    int*   degi   = (int*)ws;                      ws += (size_t)N * 4;
    float* dis    = (float*)ws;                    ws += (size_t)N * 4;
    int*   offs   = (int*)ws;                      ws += (size_t)N * 4;
    int*   cursor = (int*)ws;                      ws += (size_t)N * 4;
    int*   bsums  = (int*)ws;                      ws += 1024 * 4;
    int*   bucket = (int*)ws;

    float* out = (float*)d_out;

    hipMemsetAsync(degi,   0, (size_t)N * 4, stream);
    hipMemsetAsync(cursor, 0, (size_t)N * 4, stream);

    // 1) degree histogram
    deg_kernel<<<2048, 256, 0, stream>>>(dst, degi, E);
    // 2) dis
    dis_kernel<<<(N + 255) / 256, 256, 0, stream>>>(degi, dis, N);
    // 3) exclusive scan degi -> offs
    int nb = (N + SCAN_ELEMS - 1) / SCAN_ELEMS;
    scan1_kernel<<<nb, 256, 0, stream>>>(degi, offs, bsums, N);
    scan2_kernel<<<1, 256, 0, stream>>>(bsums, nb);
    scan3_kernel<<<(N + 255) / 256, 256, 0, stream>>>(offs, bsums, N);
    // 4) fill CSR buckets
    fill_kernel<<<2048, 256, 0, stream>>>(src, dst, offs, cursor, bucket, E);
    // 5) fused gather + self-loop + normalize + linear
    gather_linear_kernel<<<(N + 3) / 4, 256, 0, stream>>>(
        x, offs, degi, bucket, dis, W, out, N);
}

// Round 5
// 171.921 us; speedup vs baseline: 3.1998x; 1.1990x over previous
//
#include <hip/hip_runtime.h>

#define FD 64  // feature dim

// ---------------- deg + position: pos[e] = old count of dst[e] ----------------
__global__ void degpos_kernel(const int* __restrict__ dst, int* __restrict__ degi,
                              int* __restrict__ pos, int E) {
    int i = blockIdx.x * blockDim.x + threadIdx.x;
    int stride = gridDim.x * blockDim.x;
    for (; i < E; i += stride) {
        pos[i] = atomicAdd(&degi[dst[i]], 1);
    }
}

// ---------------- legacy (fallback path): plain histogram ----------------
__global__ void deg_kernel(const int* __restrict__ dst, int* __restrict__ degi, int E) {
    int i = blockIdx.x * blockDim.x + threadIdx.x;
    int stride = gridDim.x * blockDim.x;
    for (; i < E; i += stride) {
        atomicAdd(&degi[dst[i]], 1);
    }
}

// ---------------- Scan (exclusive) of degi -> offs; dis fused into pass 1 ----------------
#define SCAN_ELEMS 2048  // 256 threads x 8 elements

__global__ void scan1_kernel(const int* __restrict__ degi, int* __restrict__ offs,
                             int* __restrict__ bsums, float* __restrict__ dis, int N) {
    __shared__ int tsum[256];
    int base = blockIdx.x * SCAN_ELEMS + threadIdx.x * 8;
    int v[8];
    int s = 0;
    #pragma unroll
    for (int k = 0; k < 8; ++k) {
        int idx = base + k;
        v[k] = (idx < N) ? degi[idx] : 0;
        if (idx < N) dis[idx] = rsqrtf((float)v[k] + 1.0f);   // fused dis
        s += v[k];
    }
    tsum[threadIdx.x] = s;
    __syncthreads();
    for (int off = 1; off < 256; off <<= 1) {
        int t = (threadIdx.x >= off) ? tsum[threadIdx.x - off] : 0;
        __syncthreads();
        tsum[threadIdx.x] += t;
        __syncthreads();
    }
    int excl = (threadIdx.x == 0) ? 0 : tsum[threadIdx.x - 1];
    #pragma unroll
    for (int k = 0; k < 8; ++k) {
        int idx = base + k;
        if (idx < N) offs[idx] = excl;
        excl += v[k];
    }
    if (threadIdx.x == 255) bsums[blockIdx.x] = tsum[255];
}

__global__ void scan2_kernel(int* __restrict__ bsums, int nb) {
    __shared__ int t[256];
    int v = (threadIdx.x < nb) ? bsums[threadIdx.x] : 0;
    t[threadIdx.x] = v;
    __syncthreads();
    for (int off = 1; off < 256; off <<= 1) {
        int u = (threadIdx.x >= off) ? t[threadIdx.x - off] : 0;
        __syncthreads();
        t[threadIdx.x] += u;
        __syncthreads();
    }
    if (threadIdx.x < nb) bsums[threadIdx.x] = (threadIdx.x == 0) ? 0 : t[threadIdx.x - 1];
}

__global__ void scan3_kernel(int* __restrict__ offs, const int* __restrict__ bsums, int N) {
    int i = blockIdx.x * blockDim.x + threadIdx.x;
    if (i < N) offs[i] += bsums[i / SCAN_ELEMS];
}

// ---------------- fill CSR buckets, atomic-free (pos precomputed) ----------------
__global__ void fill_pos_kernel(const int* __restrict__ src, const int* __restrict__ dst,
                                const int* __restrict__ offs, const int* __restrict__ pos,
                                int* __restrict__ bucket, int E) {
    int i = blockIdx.x * blockDim.x + threadIdx.x;
    int stride = gridDim.x * blockDim.x;
    for (; i < E; i += stride) {
        bucket[offs[dst[i]] + pos[i]] = src[i];
    }
}

// ---------------- legacy (fallback): fill with cursor atomics ----------------
__global__ void fill_kernel(const int* __restrict__ src, const int* __restrict__ dst,
                            const int* __restrict__ offs, int* __restrict__ cursor,
                            int* __restrict__ bucket, int E) {
    int i = blockIdx.x * blockDim.x + threadIdx.x;
    int stride = gridDim.x * blockDim.x;
    for (; i < E; i += stride) {
        int d = dst[i];
        int p = atomicAdd(&cursor[d], 1);
        bucket[offs[d] + p] = src[i];
    }
}

// ---------------- z = (x @ W^T) * dis[:,None]  (streaming, W staged once/block) ----------------
#define ZR 8   // rows per wave; block covers 32 rows
__global__ __launch_bounds__(256) void z_kernel(const float* __restrict__ x,
                                                const float* __restrict__ dis,
                                                const float* __restrict__ W,
                                                float* __restrict__ z, int N) {
    __shared__ float Wt[FD][FD + 1];   // Wt[i][o] = W[o][i], padded: conflict-free
    __shared__ float rows[4][FD];

    for (int t = threadIdx.x; t < FD * FD; t += 256) {
        Wt[t & 63][t >> 6] = W[t];
    }
    __syncthreads();

    int wave = threadIdx.x >> 6;
    int lane = threadIdx.x & 63;
    int base = blockIdx.x * (4 * ZR) + wave;

    for (int r = 0; r < ZR; ++r) {
        int n = base + 4 * r;
        if (n < N) {
            rows[wave][lane] = x[(size_t)n * FD + lane];   // same-wave LDS produce/consume
            float o = 0.0f;
            #pragma unroll
            for (int i = 0; i < FD; i += 4) {
                float4 rv = *(const float4*)&rows[wave][i];  // broadcast
                o += rv.x * Wt[i + 0][lane]
                   + rv.y * Wt[i + 1][lane]
                   + rv.z * Wt[i + 2][lane]
                   + rv.w * Wt[i + 3][lane];
            }
            z[(size_t)n * FD + lane] = o * dis[n];
        }
    }
}

// ---------------- pure gather over z: out[n] = (sum z[src] + z[n]) * dis[n] ----------------
// 1 node per wave, lane = feature. No LDS, no atomics, minimal VGPR.
__global__ __launch_bounds__(256) void gather_z_kernel(
        const float* __restrict__ z, const int* __restrict__ offs,
        const int* __restrict__ degi, const int* __restrict__ bucket,
        const float* __restrict__ dis, float* __restrict__ out, int N) {
    int wave = threadIdx.x >> 6;
    int lane = threadIdx.x & 63;
    int n = blockIdx.x * 4 + wave;
    if (n >= N) return;

    int j   = offs[n];
    int end = j + degi[n];
    float acc = 0.0f;
    for (; j + 7 < end; j += 8) {   // 8 independent load chains
        int s0 = bucket[j],     s1 = bucket[j + 1], s2 = bucket[j + 2], s3 = bucket[j + 3];
        int s4 = bucket[j + 4], s5 = bucket[j + 5], s6 = bucket[j + 6], s7 = bucket[j + 7];
        float v0 = z[(size_t)s0 * FD + lane];
        float v1 = z[(size_t)s1 * FD + lane];
        float v2 = z[(size_t)s2 * FD + lane];
        float v3 = z[(size_t)s3 * FD + lane];
        float v4 = z[(size_t)s4 * FD + lane];
        float v5 = z[(size_t)s5 * FD + lane];
        float v6 = z[(size_t)s6 * FD + lane];
        float v7 = z[(size_t)s7 * FD + lane];
        acc += ((v0 + v1) + (v2 + v3)) + ((v4 + v5) + (v6 + v7));
    }
    for (; j + 3 < end; j += 4) {
        int s0 = bucket[j], s1 = bucket[j + 1], s2 = bucket[j + 2], s3 = bucket[j + 3];
        float v0 = z[(size_t)s0 * FD + lane];
        float v1 = z[(size_t)s1 * FD + lane];
        float v2 = z[(size_t)s2 * FD + lane];
        float v3 = z[(size_t)s3 * FD + lane];
        acc += (v0 + v1) + (v2 + v3);
    }
    for (; j < end; ++j) {
        acc += z[(size_t)bucket[j] * FD + lane];
    }
    out[(size_t)n * FD + lane] = (acc + z[(size_t)n * FD + lane]) * dis[n];
}

// ---------------- legacy (fallback): round-4 fused gather+linear ----------------
__global__ __launch_bounds__(256) void gather_linear_kernel(
        const float* __restrict__ x, const int* __restrict__ offs,
        const int* __restrict__ degi, const int* __restrict__ bucket,
        const float* __restrict__ dis, const float* __restrict__ W,
        float* __restrict__ out, int N) {
    __shared__ float Wt[FD][FD + 1];
    __shared__ float rows[4][FD];

    for (int t = threadIdx.x; t < FD * FD; t += 256) {
        Wt[t & 63][t >> 6] = W[t];
    }
    __syncthreads();

    int wave = threadIdx.x >> 6;
    int lane = threadIdx.x & 63;
    int n = blockIdx.x * 4 + wave;

    if (n < N) {
        int j   = offs[n];
        int end = j + degi[n];
        float acc = 0.0f;
        for (; j + 3 < end; j += 4) {
            int s0 = bucket[j], s1 = bucket[j + 1], s2 = bucket[j + 2], s3 = bucket[j + 3];
            float d0 = dis[s0], d1 = dis[s1], d2 = dis[s2], d3 = dis[s3];
            float v0 = x[(size_t)s0 * FD + lane];
            float v1 = x[(size_t)s1 * FD + lane];
            float v2 = x[(size_t)s2 * FD + lane];
            float v3 = x[(size_t)s3 * FD + lane];
            acc += v0 * d0 + v1 * d1 + v2 * d2 + v3 * d3;
        }
        for (; j < end; ++j) {
            int s = bucket[j];
            acc += x[(size_t)s * FD + lane] * dis[s];
        }
        float dn = dis[n];
        rows[wave][lane] = (acc + x[(size_t)n * FD + lane] * dn) * dn;
    }
    if (n < N) {
        float o = 0.0f;
        #pragma unroll
        for (int i = 0; i < FD; i += 4) {
            float4 r = *(const float4*)&rows[wave][i];
            o += r.x * Wt[i + 0][lane]
               + r.y * Wt[i + 1][lane]
               + r.z * Wt[i + 2][lane]
               + r.w * Wt[i + 3][lane];
        }
        out[(size_t)n * FD + lane] = o;
    }
}

extern "C" void kernel_launch(void* const* d_in, const int* in_sizes, int n_in,
                              void* d_out, int out_size, void* d_ws, size_t ws_size,
                              hipStream_t stream) {
    const float* x  = (const float*)d_in[0];
    const int*   ei = (const int*)d_in[1];   // [2, E]: src row then dst row
    const float* W  = (const float*)d_in[2];

    const int N = in_sizes[0] / FD;
    const int E = in_sizes[1] / 2;
    const int* src = ei;
    const int* dst = ei + E;

    float* out = (float*)d_out;
    const int nb = (N + SCAN_ELEMS - 1) / SCAN_ELEMS;

    // Full layout: degi[N] | dis[N] | offs[N] | bsums[1024] | pos[E] | bucket[E] | z[N*FD]
    size_t need_full = ((size_t)N * 3 + 1024 + (size_t)E * 2 + (size_t)N * FD) * 4;

    if (ws_size >= need_full) {
        char* ws = (char*)d_ws;
        int*   degi   = (int*)ws;    ws += (size_t)N * 4;
        float* dis    = (float*)ws;  ws += (size_t)N * 4;
        int*   offs   = (int*)ws;    ws += (size_t)N * 4;
        int*   bsums  = (int*)ws;    ws += 1024 * 4;
        int*   pos    = (int*)ws;    ws += (size_t)E * 4;
        int*   bucket = (int*)ws;    ws += (size_t)E * 4;
        float* z      = (float*)ws;

        hipMemsetAsync(degi, 0, (size_t)N * 4, stream);
        degpos_kernel<<<2048, 256, 0, stream>>>(dst, degi, pos, E);
        scan1_kernel<<<nb, 256, 0, stream>>>(degi, offs, bsums, dis, N);
        scan2_kernel<<<1, 256, 0, stream>>>(bsums, nb);
        scan3_kernel<<<(N + 255) / 256, 256, 0, stream>>>(offs, bsums, N);
        z_kernel<<<(N + 4 * ZR - 1) / (4 * ZR), 256, 0, stream>>>(x, dis, W, z, N);
        fill_pos_kernel<<<2048, 256, 0, stream>>>(src, dst, offs, pos, bucket, E);
        gather_z_kernel<<<(N + 3) / 4, 256, 0, stream>>>(z, offs, degi, bucket, dis, out, N);
    } else {
        // Fallback (round-4 structure): degi | dis | offs | cursor | bsums | bucket
        char* ws = (char*)d_ws;
        int*   degi   = (int*)ws;    ws += (size_t)N * 4;
        float* dis    = (float*)ws;  ws += (size_t)N * 4;
        int*   offs   = (int*)ws;    ws += (size_t)N * 4;
        int*   cursor = (int*)ws;    ws += (size_t)N * 4;
        int*   bsums  = (int*)ws;    ws += 1024 * 4;
        int*   bucket = (int*)ws;

        hipMemsetAsync(degi,   0, (size_t)N * 4, stream);
        hipMemsetAsync(cursor, 0, (size_t)N * 4, stream);
        deg_kernel<<<2048, 256, 0, stream>>>(dst, degi, E);
        scan1_kernel<<<nb, 256, 0, stream>>>(degi, offs, bsums, dis, N);
        scan2_kernel<<<1, 256, 0, stream>>>(bsums, nb);
        scan3_kernel<<<(N + 255) / 256, 256, 0, stream>>>(offs, bsums, N);
        fill_kernel<<<2048, 256, 0, stream>>>(src, dst, offs, cursor, bucket, E);
        gather_linear_kernel<<<(N + 3) / 4, 256, 0, stream>>>(
            x, offs, degi, bucket, dis, W, out, N);
    }
}

// Round 6
// 141.221 us; speedup vs baseline: 3.8954x; 1.2174x over previous
//
#include <hip/hip_runtime.h>

#define FD 64  // feature dim

typedef __attribute__((ext_vector_type(8))) short bf16x8;
typedef __attribute__((ext_vector_type(4))) float f32x4;

__device__ inline short f2bf(float f) {   // fp32 -> bf16 RNE
    union { float f; unsigned u; } v; v.f = f;
    unsigned r = (v.u + 0x7fffu + ((v.u >> 16) & 1u)) >> 16;
    return (short)r;
}

// ---------------- deg + position: pos[e] = old count of dst[e] ----------------
__global__ void degpos_kernel(const int* __restrict__ dst, int* __restrict__ degi,
                              int* __restrict__ pos, int E) {
    int i = blockIdx.x * blockDim.x + threadIdx.x;
    int stride = gridDim.x * blockDim.x;
    for (; i < E; i += stride) {
        pos[i] = atomicAdd(&degi[dst[i]], 1);
    }
}

// ---------------- Scan (exclusive) of degi -> offs; dis fused into pass 1 ----------------
#define SCAN_ELEMS 2048  // 256 threads x 8 elements

__global__ void scan1_kernel(const int* __restrict__ degi, int* __restrict__ offs,
                             int* __restrict__ bsums, float* __restrict__ dis, int N) {
    __shared__ int tsum[256];
    int base = blockIdx.x * SCAN_ELEMS + threadIdx.x * 8;
    int v[8];
    int s = 0;
    #pragma unroll
    for (int k = 0; k < 8; ++k) {
        int idx = base + k;
        v[k] = (idx < N) ? degi[idx] : 0;
        if (idx < N) dis[idx] = rsqrtf((float)v[k] + 1.0f);   // fused dis
        s += v[k];
    }
    tsum[threadIdx.x] = s;
    __syncthreads();
    for (int off = 1; off < 256; off <<= 1) {
        int t = (threadIdx.x >= off) ? tsum[threadIdx.x - off] : 0;
        __syncthreads();
        tsum[threadIdx.x] += t;
        __syncthreads();
    }
    int excl = (threadIdx.x == 0) ? 0 : tsum[threadIdx.x - 1];
    #pragma unroll
    for (int k = 0; k < 8; ++k) {
        int idx = base + k;
        if (idx < N) offs[idx] = excl;
        excl += v[k];
    }
    if (threadIdx.x == 255) bsums[blockIdx.x] = tsum[255];
}

__global__ void scan2_kernel(int* __restrict__ bsums, int nb) {
    __shared__ int t[256];
    int v = (threadIdx.x < nb) ? bsums[threadIdx.x] : 0;
    t[threadIdx.x] = v;
    __syncthreads();
    for (int off = 1; off < 256; off <<= 1) {
        int u = (threadIdx.x >= off) ? t[threadIdx.x - off] : 0;
        __syncthreads();
        t[threadIdx.x] += u;
        __syncthreads();
    }
    if (threadIdx.x < nb) bsums[threadIdx.x] = (threadIdx.x == 0) ? 0 : t[threadIdx.x - 1];
}

__global__ void scan3_kernel(int* __restrict__ offs, const int* __restrict__ bsums, int N) {
    int i = blockIdx.x * blockDim.x + threadIdx.x;
    if (i < N) offs[i] += bsums[i / SCAN_ELEMS];
}

// ---------------- fill CSR buckets, atomic-free (pos precomputed) ----------------
__global__ void fill_pos_kernel(const int* __restrict__ src, const int* __restrict__ dst,
                                const int* __restrict__ offs, const int* __restrict__ pos,
                                int* __restrict__ bucket, int E) {
    int i = blockIdx.x * blockDim.x + threadIdx.x;
    int stride = gridDim.x * blockDim.x;
    for (; i < E; i += stride) {
        bucket[offs[dst[i]] + pos[i]] = src[i];
    }
}

// ---------------- z = (x @ W^T) * dis[:,None] via MFMA ----------------
// One wave per 16-row tile, covering all 64 output cols. W (B-operand) is
// converted to bf16 fragments ONCE per wave and lives in registers; steady
// state = 4 dwordx4 loads of x + 16 cvt + 8 MFMA + 16 stores. Zero LDS.
// Fragment layouts (m89-verified family):
//   A: row = lane&15,  k = 8*(lane>>4) + b
//   B: col = lane&15,  k = 8*(lane>>4) + b
//   D: col = lane&15,  row = 4*(lane>>4) + reg
__global__ __launch_bounds__(256) void z_mfma_kernel(
        const float* __restrict__ x, const float* __restrict__ dis,
        const float* __restrict__ W, float* __restrict__ z, int N) {
    int lane = threadIdx.x & 63;
    int r16  = lane & 15;
    int kg   = lane >> 4;   // 0..3

    // B fragments: bfrag[ct][kk] covers cols [16ct,16ct+16), k-chunk kk*32..+32
    bf16x8 bfrag[4][2];
    #pragma unroll
    for (int ct = 0; ct < 4; ++ct) {
        #pragma unroll
        for (int kk = 0; kk < 2; ++kk) {
            // B[k][col] = W[col][k]; col = ct*16 + r16, k = kk*32 + kg*8 + b
            const float* wp = W + (size_t)(ct * 16 + r16) * FD + kk * 32 + kg * 8;
            float4 w0 = *(const float4*)wp;
            float4 w1 = *(const float4*)(wp + 4);
            bf16x8 b;
            b[0] = f2bf(w0.x); b[1] = f2bf(w0.y); b[2] = f2bf(w0.z); b[3] = f2bf(w0.w);
            b[4] = f2bf(w1.x); b[5] = f2bf(w1.y); b[6] = f2bf(w1.z); b[7] = f2bf(w1.w);
            bfrag[ct][kk] = b;
        }
    }

    int wid    = blockIdx.x * (blockDim.x >> 6) + (threadIdx.x >> 6);
    int nwaves = gridDim.x * (blockDim.x >> 6);
    int tiles  = (N + 15) >> 4;

    for (int t = wid; t < tiles; t += nwaves) {
        int n0  = t << 4;
        int row = n0 + r16;
        int rl  = row < N ? row : N - 1;          // clamp: extra rows never stored
        const float* xp = x + (size_t)rl * FD + kg * 8;
        float4 a00 = *(const float4*)(xp);        // k-chunk 0
        float4 a01 = *(const float4*)(xp + 4);
        float4 a10 = *(const float4*)(xp + 32);   // k-chunk 1
        float4 a11 = *(const float4*)(xp + 36);
        bf16x8 a0, a1;
        a0[0] = f2bf(a00.x); a0[1] = f2bf(a00.y); a0[2] = f2bf(a00.z); a0[3] = f2bf(a00.w);
        a0[4] = f2bf(a01.x); a0[5] = f2bf(a01.y); a0[6] = f2bf(a01.z); a0[7] = f2bf(a01.w);
        a1[0] = f2bf(a10.x); a1[1] = f2bf(a10.y); a1[2] = f2bf(a10.z); a1[3] = f2bf(a10.w);
        a1[4] = f2bf(a11.x); a1[5] = f2bf(a11.y); a1[6] = f2bf(a11.z); a1[7] = f2bf(a11.w);

        f32x4 acc[4];
        #pragma unroll
        for (int ct = 0; ct < 4; ++ct) {
            acc[ct] = (f32x4){0.f, 0.f, 0.f, 0.f};
            acc[ct] = __builtin_amdgcn_mfma_f32_16x16x32_bf16(a0, bfrag[ct][0], acc[ct], 0, 0, 0);
            acc[ct] = __builtin_amdgcn_mfma_f32_16x16x32_bf16(a1, bfrag[ct][1], acc[ct], 0, 0, 0);
        }

        #pragma unroll
        for (int reg = 0; reg < 4; ++reg) {
            int nr = n0 + kg * 4 + reg;           // D row
            if (nr < N) {
                float dn = dis[nr];
                #pragma unroll
                for (int ct = 0; ct < 4; ++ct) {
                    z[(size_t)nr * FD + ct * 16 + r16] = acc[ct][reg] * dn;
                }
            }
        }
    }
}

// ---------------- pure gather over z: out[n] = (sum z[src] + z[n]) * dis[n] ----------------
__global__ __launch_bounds__(256) void gather_z_kernel(
        const float* __restrict__ z, const int* __restrict__ offs,
        const int* __restrict__ degi, const int* __restrict__ bucket,
        const float* __restrict__ dis, float* __restrict__ out, int N) {
    int wave = threadIdx.x >> 6;
    int lane = threadIdx.x & 63;
    int n = blockIdx.x * 4 + wave;
    if (n >= N) return;

    int j   = offs[n];
    int end = j + degi[n];
    float acc = 0.0f;
    for (; j + 7 < end; j += 8) {   // 8 independent load chains
        int s0 = bucket[j],     s1 = bucket[j + 1], s2 = bucket[j + 2], s3 = bucket[j + 3];
        int s4 = bucket[j + 4], s5 = bucket[j + 5], s6 = bucket[j + 6], s7 = bucket[j + 7];
        float v0 = z[(size_t)s0 * FD + lane];
        float v1 = z[(size_t)s1 * FD + lane];
        float v2 = z[(size_t)s2 * FD + lane];
        float v3 = z[(size_t)s3 * FD + lane];
        float v4 = z[(size_t)s4 * FD + lane];
        float v5 = z[(size_t)s5 * FD + lane];
        float v6 = z[(size_t)s6 * FD + lane];
        float v7 = z[(size_t)s7 * FD + lane];
        acc += ((v0 + v1) + (v2 + v3)) + ((v4 + v5) + (v6 + v7));
    }
    for (; j + 3 < end; j += 4) {
        int s0 = bucket[j], s1 = bucket[j + 1], s2 = bucket[j + 2], s3 = bucket[j + 3];
        float v0 = z[(size_t)s0 * FD + lane];
        float v1 = z[(size_t)s1 * FD + lane];
        float v2 = z[(size_t)s2 * FD + lane];
        float v3 = z[(size_t)s3 * FD + lane];
        acc += (v0 + v1) + (v2 + v3);
    }
    for (; j < end; ++j) {
        acc += z[(size_t)bucket[j] * FD + lane];
    }
    out[(size_t)n * FD + lane] = (acc + z[(size_t)n * FD + lane]) * dis[n];
}

// ---------------- fallback (ws too small): round-4 fused gather+linear ----------------
__global__ void deg_kernel(const int* __restrict__ dst, int* __restrict__ degi, int E) {
    int i = blockIdx.x * blockDim.x + threadIdx.x;
    int stride = gridDim.x * blockDim.x;
    for (; i < E; i += stride) {
        atomicAdd(&degi[dst[i]], 1);
    }
}

__global__ void fill_kernel(const int* __restrict__ src, const int* __restrict__ dst,
                            const int* __restrict__ offs, int* __restrict__ cursor,
                            int* __restrict__ bucket, int E) {
    int i = blockIdx.x * blockDim.x + threadIdx.x;
    int stride = gridDim.x * blockDim.x;
    for (; i < E; i += stride) {
        int d = dst[i];
        int p = atomicAdd(&cursor[d], 1);
        bucket[offs[d] + p] = src[i];
    }
}

__global__ __launch_bounds__(256) void gather_linear_kernel(
        const float* __restrict__ x, const int* __restrict__ offs,
        const int* __restrict__ degi, const int* __restrict__ bucket,
        const float* __restrict__ dis, const float* __restrict__ W,
        float* __restrict__ out, int N) {
    __shared__ float Wt[FD][FD + 1];
    __shared__ float rows[4][FD];

    for (int t = threadIdx.x; t < FD * FD; t += 256) {
        Wt[t & 63][t >> 6] = W[t];
    }
    __syncthreads();

    int wave = threadIdx.x >> 6;
    int lane = threadIdx.x & 63;
    int n = blockIdx.x * 4 + wave;

    if (n < N) {
        int j   = offs[n];
        int end = j + degi[n];
        float acc = 0.0f;
        for (; j + 3 < end; j += 4) {
            int s0 = bucket[j], s1 = bucket[j + 1], s2 = bucket[j + 2], s3 = bucket[j + 3];
            float d0 = dis[s0], d1 = dis[s1], d2 = dis[s2], d3 = dis[s3];
            float v0 = x[(size_t)s0 * FD + lane];
            float v1 = x[(size_t)s1 * FD + lane];
            float v2 = x[(size_t)s2 * FD + lane];
            float v3 = x[(size_t)s3 * FD + lane];
            acc += v0 * d0 + v1 * d1 + v2 * d2 + v3 * d3;
        }
        for (; j < end; ++j) {
            int s = bucket[j];
            acc += x[(size_t)s * FD + lane] * dis[s];
        }
        float dn = dis[n];
        rows[wave][lane] = (acc + x[(size_t)n * FD + lane] * dn) * dn;
    }
    if (n < N) {
        float o = 0.0f;
        #pragma unroll
        for (int i = 0; i < FD; i += 4) {
            float4 r = *(const float4*)&rows[wave][i];
            o += r.x * Wt[i + 0][lane]
               + r.y * Wt[i + 1][lane]
               + r.z * Wt[i + 2][lane]
               + r.w * Wt[i + 3][lane];
        }
        out[(size_t)n * FD + lane] = o;
    }
}

extern "C" void kernel_launch(void* const* d_in, const int* in_sizes, int n_in,
                              void* d_out, int out_size, void* d_ws, size_t ws_size,
                              hipStream_t stream) {
    const float* x  = (const float*)d_in[0];
    const int*   ei = (const int*)d_in[1];   // [2, E]: src row then dst row
    const float* W  = (const float*)d_in[2];

    const int N = in_sizes[0] / FD;
    const int E = in_sizes[1] / 2;
    const int* src = ei;
    const int* dst = ei + E;

    float* out = (float*)d_out;
    const int nb = (N + SCAN_ELEMS - 1) / SCAN_ELEMS;

    // Full layout: degi[N] | dis[N] | offs[N] | bsums[1024] | pos[E] | bucket[E] | z[N*FD]
    size_t need_full = ((size_t)N * 3 + 1024 + (size_t)E * 2 + (size_t)N * FD) * 4;

    if (ws_size >= need_full) {
        char* ws = (char*)d_ws;
        int*   degi   = (int*)ws;    ws += (size_t)N * 4;
        float* dis    = (float*)ws;  ws += (size_t)N * 4;
        int*   offs   = (int*)ws;    ws += (size_t)N * 4;
        int*   bsums  = (int*)ws;    ws += 1024 * 4;
        int*   pos    = (int*)ws;    ws += (size_t)E * 4;
        int*   bucket = (int*)ws;    ws += (size_t)E * 4;
        float* z      = (float*)ws;

        hipMemsetAsync(degi, 0, (size_t)N * 4, stream);
        degpos_kernel<<<2048, 256, 0, stream>>>(dst, degi, pos, E);
        scan1_kernel<<<nb, 256, 0, stream>>>(degi, offs, bsums, dis, N);
        scan2_kernel<<<1, 256, 0, stream>>>(bsums, nb);
        scan3_kernel<<<(N + 255) / 256, 256, 0, stream>>>(offs, bsums, N);
        z_mfma_kernel<<<512, 256, 0, stream>>>(x, dis, W, z, N);
        fill_pos_kernel<<<2048, 256, 0, stream>>>(src, dst, offs, pos, bucket, E);
        gather_z_kernel<<<(N + 3) / 4, 256, 0, stream>>>(z, offs, degi, bucket, dis, out, N);
    } else {
        // Fallback (round-4 structure): degi | dis | offs | cursor | bsums | bucket
        char* ws = (char*)d_ws;
        int*   degi   = (int*)ws;    ws += (size_t)N * 4;
        float* dis    = (float*)ws;  ws += (size_t)N * 4;
        int*   offs   = (int*)ws;    ws += (size_t)N * 4;
        int*   cursor = (int*)ws;    ws += (size_t)N * 4;
        int*   bsums  = (int*)ws;    ws += 1024 * 4;
        int*   bucket = (int*)ws;

        hipMemsetAsync(degi,   0, (size_t)N * 4, stream);
        hipMemsetAsync(cursor, 0, (size_t)N * 4, stream);
        deg_kernel<<<2048, 256, 0, stream>>>(dst, degi, E);
        scan1_kernel<<<nb, 256, 0, stream>>>(degi, offs, bsums, dis, N);
        scan2_kernel<<<1, 256, 0, stream>>>(bsums, nb);
        scan3_kernel<<<(N + 255) / 256, 256, 0, stream>>>(offs, bsums, N);
        fill_kernel<<<2048, 256, 0, stream>>>(src, dst, offs, cursor, bucket, E);
        gather_linear_kernel<<<(N + 3) / 4, 256, 0, stream>>>(
            x, offs, degi, bucket, dis, W, out, N);
    }
}

// Round 7
// 134.815 us; speedup vs baseline: 4.0805x; 1.0475x over previous
//
#include <hip/hip_runtime.h>

#define FD 64  // feature dim

typedef __attribute__((ext_vector_type(8))) short bf16x8;
typedef __attribute__((ext_vector_type(4))) float f32x4;

__device__ inline short f2bf(float f) {   // fp32 -> bf16 RNE
    union { float f; unsigned u; } v; v.f = f;
    unsigned r = (v.u + 0x7fffu + ((v.u >> 16) & 1u)) >> 16;
    return (short)r;
}
__device__ inline float bf2f(unsigned short u) {
    union { unsigned u; float f; } v; v.u = ((unsigned)u) << 16;
    return v.f;
}

// ---------------- deg + position: pos[e] = old count of dst[e] ----------------
__global__ void degpos_kernel(const int* __restrict__ dst, int* __restrict__ degi,
                              unsigned short* __restrict__ pos, int E) {
    int i = blockIdx.x * blockDim.x + threadIdx.x;
    int stride = gridDim.x * blockDim.x;
    for (; i < E; i += stride) {
        pos[i] = (unsigned short)atomicAdd(&degi[dst[i]], 1);
    }
}

// ---------------- Scan (exclusive) of degi -> offs (block-local); dis fused ----------------
#define SCAN_ELEMS 2048  // 256 threads x 8 elements

__global__ void scan1_kernel(const int* __restrict__ degi, int* __restrict__ offs,
                             int* __restrict__ bsums, float* __restrict__ dis, int N) {
    __shared__ int tsum[256];
    int base = blockIdx.x * SCAN_ELEMS + threadIdx.x * 8;
    int v[8];
    int s = 0;
    #pragma unroll
    for (int k = 0; k < 8; ++k) {
        int idx = base + k;
        v[k] = (idx < N) ? degi[idx] : 0;
        if (idx < N) dis[idx] = rsqrtf((float)v[k] + 1.0f);   // fused dis
        s += v[k];
    }
    tsum[threadIdx.x] = s;
    __syncthreads();
    for (int off = 1; off < 256; off <<= 1) {
        int t = (threadIdx.x >= off) ? tsum[threadIdx.x - off] : 0;
        __syncthreads();
        tsum[threadIdx.x] += t;
        __syncthreads();
    }
    int excl = (threadIdx.x == 0) ? 0 : tsum[threadIdx.x - 1];
    #pragma unroll
    for (int k = 0; k < 8; ++k) {
        int idx = base + k;
        if (idx < N) offs[idx] = excl;    // BLOCK-LOCAL exclusive scan
        excl += v[k];
    }
    if (threadIdx.x == 255) bsums[blockIdx.x] = tsum[255];
}

__global__ void scan2_kernel(int* __restrict__ bsums, int nb) {
    __shared__ int t[256];
    int v = (threadIdx.x < nb) ? bsums[threadIdx.x] : 0;
    t[threadIdx.x] = v;
    __syncthreads();
    for (int off = 1; off < 256; off <<= 1) {
        int u = (threadIdx.x >= off) ? t[threadIdx.x - off] : 0;
        __syncthreads();
        t[threadIdx.x] += u;
        __syncthreads();
    }
    if (threadIdx.x < nb) bsums[threadIdx.x] = (threadIdx.x == 0) ? 0 : t[threadIdx.x - 1];
}

// scan3 (fallback path only): materialize global offs
__global__ void scan3_kernel(int* __restrict__ offs, const int* __restrict__ bsums, int N) {
    int i = blockIdx.x * blockDim.x + threadIdx.x;
    if (i < N) offs[i] += bsums[i / SCAN_ELEMS];
}

// ---------------- fill CSR buckets, atomic-free; bsums folded in ----------------
__global__ void fill_pos_kernel(const int* __restrict__ src, const int* __restrict__ dst,
                                const int* __restrict__ offs, const int* __restrict__ bsums,
                                const unsigned short* __restrict__ pos,
                                int* __restrict__ bucket, int E) {
    int i = blockIdx.x * blockDim.x + threadIdx.x;
    int stride = gridDim.x * blockDim.x;
    for (; i < E; i += stride) {
        int d = dst[i];
        bucket[offs[d] + bsums[d >> 11] + (int)pos[i]] = src[i];
    }
}

// ---------------- z = bf16( (x @ W^T) * dis[:,None] ) via MFMA ----------------
// One wave per 16-row tile, all 64 output cols. W fragments live in registers.
// Fragment layouts (m89-verified family):
//   A: row = lane&15,  k = 8*(lane>>4) + b
//   B: col = lane&15,  k = 8*(lane>>4) + b
//   D: col = lane&15,  row = 4*(lane>>4) + reg
__global__ __launch_bounds__(256) void z_mfma_kernel(
        const float* __restrict__ x, const float* __restrict__ dis,
        const float* __restrict__ W, unsigned short* __restrict__ z, int N) {
    int lane = threadIdx.x & 63;
    int r16  = lane & 15;
    int kg   = lane >> 4;   // 0..3

    bf16x8 bfrag[4][2];
    #pragma unroll
    for (int ct = 0; ct < 4; ++ct) {
        #pragma unroll
        for (int kk = 0; kk < 2; ++kk) {
            const float* wp = W + (size_t)(ct * 16 + r16) * FD + kk * 32 + kg * 8;
            float4 w0 = *(const float4*)wp;
            float4 w1 = *(const float4*)(wp + 4);
            bf16x8 b;
            b[0] = f2bf(w0.x); b[1] = f2bf(w0.y); b[2] = f2bf(w0.z); b[3] = f2bf(w0.w);
            b[4] = f2bf(w1.x); b[5] = f2bf(w1.y); b[6] = f2bf(w1.z); b[7] = f2bf(w1.w);
            bfrag[ct][kk] = b;
        }
    }

    int wid    = blockIdx.x * (blockDim.x >> 6) + (threadIdx.x >> 6);
    int nwaves = gridDim.x * (blockDim.x >> 6);
    int tiles  = (N + 15) >> 4;

    for (int t = wid; t < tiles; t += nwaves) {
        int n0  = t << 4;
        int row = n0 + r16;
        int rl  = row < N ? row : N - 1;          // clamp: extra rows never stored
        const float* xp = x + (size_t)rl * FD + kg * 8;
        float4 a00 = *(const float4*)(xp);
        float4 a01 = *(const float4*)(xp + 4);
        float4 a10 = *(const float4*)(xp + 32);
        float4 a11 = *(const float4*)(xp + 36);
        bf16x8 a0, a1;
        a0[0] = f2bf(a00.x); a0[1] = f2bf(a00.y); a0[2] = f2bf(a00.z); a0[3] = f2bf(a00.w);
        a0[4] = f2bf(a01.x); a0[5] = f2bf(a01.y); a0[6] = f2bf(a01.z); a0[7] = f2bf(a01.w);
        a1[0] = f2bf(a10.x); a1[1] = f2bf(a10.y); a1[2] = f2bf(a10.z); a1[3] = f2bf(a10.w);
        a1[4] = f2bf(a11.x); a1[5] = f2bf(a11.y); a1[6] = f2bf(a11.z); a1[7] = f2bf(a11.w);

        f32x4 acc[4];
        #pragma unroll
        for (int ct = 0; ct < 4; ++ct) {
            acc[ct] = (f32x4){0.f, 0.f, 0.f, 0.f};
            acc[ct] = __builtin_amdgcn_mfma_f32_16x16x32_bf16(a0, bfrag[ct][0], acc[ct], 0, 0, 0);
            acc[ct] = __builtin_amdgcn_mfma_f32_16x16x32_bf16(a1, bfrag[ct][1], acc[ct], 0, 0, 0);
        }

        #pragma unroll
        for (int reg = 0; reg < 4; ++reg) {
            int nr = n0 + kg * 4 + reg;
            if (nr < N) {
                float dn = dis[nr];
                #pragma unroll
                for (int ct = 0; ct < 4; ++ct) {
                    z[(size_t)nr * FD + ct * 16 + r16] =
                        (unsigned short)f2bf(acc[ct][reg] * dn);
                }
            }
        }
    }
}

// ---------------- pure gather over bf16 z: out[n] = (sum z[src] + z[n]) * dis[n] ----------------
__global__ __launch_bounds__(256) void gather_z_kernel(
        const unsigned short* __restrict__ z, const int* __restrict__ offs,
        const int* __restrict__ bsums, const int* __restrict__ degi,
        const int* __restrict__ bucket, const float* __restrict__ dis,
        float* __restrict__ out, int N) {
    int wave = threadIdx.x >> 6;
    int lane = threadIdx.x & 63;
    int n = blockIdx.x * 4 + wave;
    if (n >= N) return;

    const unsigned short* zl = z + lane;
    int j   = offs[n] + bsums[n >> 11];
    int end = j + degi[n];
    float acc = 0.0f;
    for (; j + 7 < end; j += 8) {   // 8 independent load chains
        int s0 = bucket[j],     s1 = bucket[j + 1], s2 = bucket[j + 2], s3 = bucket[j + 3];
        int s4 = bucket[j + 4], s5 = bucket[j + 5], s6 = bucket[j + 6], s7 = bucket[j + 7];
        float v0 = bf2f(zl[(size_t)s0 * FD]);
        float v1 = bf2f(zl[(size_t)s1 * FD]);
        float v2 = bf2f(zl[(size_t)s2 * FD]);
        float v3 = bf2f(zl[(size_t)s3 * FD]);
        float v4 = bf2f(zl[(size_t)s4 * FD]);
        float v5 = bf2f(zl[(size_t)s5 * FD]);
        float v6 = bf2f(zl[(size_t)s6 * FD]);
        float v7 = bf2f(zl[(size_t)s7 * FD]);
        acc += ((v0 + v1) + (v2 + v3)) + ((v4 + v5) + (v6 + v7));
    }
    for (; j + 3 < end; j += 4) {
        int s0 = bucket[j], s1 = bucket[j + 1], s2 = bucket[j + 2], s3 = bucket[j + 3];
        float v0 = bf2f(zl[(size_t)s0 * FD]);
        float v1 = bf2f(zl[(size_t)s1 * FD]);
        float v2 = bf2f(zl[(size_t)s2 * FD]);
        float v3 = bf2f(zl[(size_t)s3 * FD]);
        acc += (v0 + v1) + (v2 + v3);
    }
    for (; j < end; ++j) {
        acc += bf2f(zl[(size_t)bucket[j] * FD]);
    }
    out[(size_t)n * FD + lane] = (acc + bf2f(zl[(size_t)n * FD])) * dis[n];
}

// ---------------- fallback (ws too small): round-4 fused path ----------------
__global__ void deg_kernel(const int* __restrict__ dst, int* __restrict__ degi, int E) {
    int i = blockIdx.x * blockDim.x + threadIdx.x;
    int stride = gridDim.x * blockDim.x;
    for (; i < E; i += stride) {
        atomicAdd(&degi[dst[i]], 1);
    }
}

__global__ void fill_kernel(const int* __restrict__ src, const int* __restrict__ dst,
                            const int* __restrict__ offs, int* __restrict__ cursor,
                            int* __restrict__ bucket, int E) {
    int i = blockIdx.x * blockDim.x + threadIdx.x;
    int stride = gridDim.x * blockDim.x;
    for (; i < E; i += stride) {
        int d = dst[i];
        int p = atomicAdd(&cursor[d], 1);
        bucket[offs[d] + p] = src[i];
    }
}

__global__ __launch_bounds__(256) void gather_linear_kernel(
        const float* __restrict__ x, const int* __restrict__ offs,
        const int* __restrict__ degi, const int* __restrict__ bucket,
        const float* __restrict__ dis, const float* __restrict__ W,
        float* __restrict__ out, int N) {
    __shared__ float Wt[FD][FD + 1];
    __shared__ float rows[4][FD];

    for (int t = threadIdx.x; t < FD * FD; t += 256) {
        Wt[t & 63][t >> 6] = W[t];
    }
    __syncthreads();

    int wave = threadIdx.x >> 6;
    int lane = threadIdx.x & 63;
    int n = blockIdx.x * 4 + wave;

    if (n < N) {
        int j   = offs[n];
        int end = j + degi[n];
        float acc = 0.0f;
        for (; j + 3 < end; j += 4) {
            int s0 = bucket[j], s1 = bucket[j + 1], s2 = bucket[j + 2], s3 = bucket[j + 3];
            float d0 = dis[s0], d1 = dis[s1], d2 = dis[s2], d3 = dis[s3];
            float v0 = x[(size_t)s0 * FD + lane];
            float v1 = x[(size_t)s1 * FD + lane];
            float v2 = x[(size_t)s2 * FD + lane];
            float v3 = x[(size_t)s3 * FD + lane];
            acc += v0 * d0 + v1 * d1 + v2 * d2 + v3 * d3;
        }
        for (; j < end; ++j) {
            int s = bucket[j];
            acc += x[(size_t)s * FD + lane] * dis[s];
        }
        float dn = dis[n];
        rows[wave][lane] = (acc + x[(size_t)n * FD + lane] * dn) * dn;
    }
    if (n < N) {
        float o = 0.0f;
        #pragma unroll
        for (int i = 0; i < FD; i += 4) {
            float4 r = *(const float4*)&rows[wave][i];
            o += r.x * Wt[i + 0][lane]
               + r.y * Wt[i + 1][lane]
               + r.z * Wt[i + 2][lane]
               + r.w * Wt[i + 3][lane];
        }
        out[(size_t)n * FD + lane] = o;
    }
}

extern "C" void kernel_launch(void* const* d_in, const int* in_sizes, int n_in,
                              void* d_out, int out_size, void* d_ws, size_t ws_size,
                              hipStream_t stream) {
    const float* x  = (const float*)d_in[0];
    const int*   ei = (const int*)d_in[1];   // [2, E]: src row then dst row
    const float* W  = (const float*)d_in[2];

    const int N = in_sizes[0] / FD;
    const int E = in_sizes[1] / 2;
    const int* src = ei;
    const int* dst = ei + E;

    float* out = (float*)d_out;
    const int nb = (N + SCAN_ELEMS - 1) / SCAN_ELEMS;

    // Full layout: degi[N] | dis[N] | offs[N] | bsums[1024] | bucket[E] | pos[E]u16 | z[N*FD]bf16
    size_t posB = (((size_t)E * 2) + 3) & ~(size_t)3;
    size_t need_full = ((size_t)N * 3 + 1024 + (size_t)E) * 4 + posB + (size_t)N * FD * 2;

    if (ws_size >= need_full) {
        char* ws = (char*)d_ws;
        int*   degi   = (int*)ws;    ws += (size_t)N * 4;
        float* dis    = (float*)ws;  ws += (size_t)N * 4;
        int*   offs   = (int*)ws;    ws += (size_t)N * 4;
        int*   bsums  = (int*)ws;    ws += 1024 * 4;
        int*   bucket = (int*)ws;    ws += (size_t)E * 4;
        unsigned short* pos = (unsigned short*)ws;  ws += posB;
        unsigned short* z   = (unsigned short*)ws;

        hipMemsetAsync(degi, 0, (size_t)N * 4, stream);
        degpos_kernel<<<2048, 256, 0, stream>>>(dst, degi, pos, E);
        scan1_kernel<<<nb, 256, 0, stream>>>(degi, offs, bsums, dis, N);
        scan2_kernel<<<1, 256, 0, stream>>>(bsums, nb);
        z_mfma_kernel<<<512, 256, 0, stream>>>(x, dis, W, z, N);
        fill_pos_kernel<<<2048, 256, 0, stream>>>(src, dst, offs, bsums, pos, bucket, E);
        gather_z_kernel<<<(N + 3) / 4, 256, 0, stream>>>(z, offs, bsums, degi, bucket, dis, out, N);
    } else {
        // Fallback (round-4 structure): degi | dis | offs | cursor | bsums | bucket
        char* ws = (char*)d_ws;
        int*   degi   = (int*)ws;    ws += (size_t)N * 4;
        float* dis    = (float*)ws;  ws += (size_t)N * 4;
        int*   offs   = (int*)ws;    ws += (size_t)N * 4;
        int*   cursor = (int*)ws;    ws += (size_t)N * 4;
        int*   bsums  = (int*)ws;    ws += 1024 * 4;
        int*   bucket = (int*)ws;

        hipMemsetAsync(degi,   0, (size_t)N * 4, stream);
        hipMemsetAsync(cursor, 0, (size_t)N * 4, stream);
        deg_kernel<<<2048, 256, 0, stream>>>(dst, degi, E);
        scan1_kernel<<<nb, 256, 0, stream>>>(degi, offs, bsums, dis, N);
        scan2_kernel<<<1, 256, 0, stream>>>(bsums, nb);
        scan3_kernel<<<(N + 255) / 256, 256, 0, stream>>>(offs, bsums, N);
        fill_kernel<<<2048, 256, 0, stream>>>(src, dst, offs, cursor, bucket, E);
        gather_linear_kernel<<<(N + 3) / 4, 256, 0, stream>>>(
            x, offs, degi, bucket, dis, W, out, N);
    }
}